// Round 8
// baseline (125.686 us; speedup 1.0000x reference)
//
#include <hip/hip_runtime.h>

typedef long long i64;
typedef unsigned long long u64;

// ---------------------------------------------------------------------------
// Established facts (R1-R7):
//  - int64 inputs; int32 output layout [total*3] neg then [total] keep.
//  - R4 (this exact structure minus the tail fast path): PASSED, 53 us,
//    VALUBusy 45%, occupancy 72%, FETCH 9.5 MB, WRITE 65.5 MB exact ->
//    latency-bound on divergent binary-search line requests.
//  - Aborts are unreliable kernel evidence on this node: R1 aborted with a
//    kernel proven innocent by R4; R0/R3 were container failures. R5-R7
//    (d_ws/atomics/ballot variants) all aborted -> stay strictly inside the
//    R4-proven structural class: ONE dispatch, template+width-probe, no
//    d_ws, no atomics, no cross-lane intrinsics.
// This round: tail-wave prefix search WITHOUT any wave intrinsic.
//  num_negs==64 and split%64==0 => corrupt side and (h,r,t) are wave-uniform
//  per construction; the `i >= split` branch is divergence-free. Tail waves
//  share the 42-bit (h,r) key prefix, so one BROADCAST lower_bound (all
//  lanes probe identical addresses: 1 line request/level instead of <=64)
//  plus a ~0-length forward scan replaces 64 divergent 20-level searches.
// ---------------------------------------------------------------------------

template <typename T>
__device__ __forceinline__ int lower_bound_idx(const T* __restrict__ table,
                                               int L, u64 key) {
    int low = 0, size = L;
    while (size > 0) {
        int half = size >> 1;
        int mid = low + half;
        u64 v = (u64)table[mid];
        if (v < key) { low = mid + 1; size -= half + 1; }
        else         { size = half; }
    }
    return low;
}

template <typename T>
__device__ __forceinline__ void sample_body(
    const T* __restrict__ pos, const T* __restrict__ rand_vals,
    const T* __restrict__ table,
    int* __restrict__ out_neg, int* __restrict__ out_keep,
    unsigned i, int split, int L, unsigned num_negs, bool uniform_ok)
{
    unsigned b = i / num_negs;   // num_negs=64 -> shift
    i64 h = (i64)pos[3 * b + 0];
    i64 r = (i64)pos[3 * b + 1];
    i64 t = (i64)pos[3 * b + 2];
    i64 rv = (i64)rand_vals[i];

    const bool corrupt_head = (i < (unsigned)split);
    i64 orig = corrupt_head ? h : t;
    // pad_idx==0 fast path: rng drawn in [1, NUM_ENTITIES); shift past original
    i64 repl = rv + (((rv >= orig) & (orig > 0)) ? 1 : 0);
    if (corrupt_head) h = repl; else t = repl;

    u64 key = ((u64)h << 42) | ((u64)r << 21) | (u64)t;

    bool in_set;
    if (uniform_ok && !corrupt_head) {
        // Tail wave: (h,r) wave-uniform -> broadcast search for the first
        // entry with prefix (h,r) (t=0 sentinel key; real t >= 1), then scan
        // the contiguous prefix range (expected length L/(NE*NR) ~= 0.01).
        u64 P = ((u64)h << 42) | ((u64)r << 21);
        int lo = lower_bound_idx(table, L, P);
        in_set = false;
        for (int j = lo; j < L; ++j) {
            u64 v = (u64)table[j];
            if ((v >> 21) != (P >> 21)) break;   // left the (h,r) range
            if (v == key) { in_set = true; break; }
        }
    } else {
        // Head wave (h diverges in the key's top bits): per-lane search.
        int low = lower_bound_idx(table, L, key);
        in_set = (low < L) && ((u64)table[low] == key);
    }

    out_neg[3 * (size_t)i + 0] = (int)h;
    out_neg[3 * (size_t)i + 1] = (int)r;
    out_neg[3 * (size_t)i + 2] = (int)t;
    out_keep[i] = in_set ? 0 : 1;
}

__global__ __launch_bounds__(256) void neg_sample_kernel(
    const void* __restrict__ pos, const void* __restrict__ rand_vals,
    const void* __restrict__ table,
    int* __restrict__ out_neg, int* __restrict__ out_keep,
    int total, int split, int L, unsigned num_negs, int uniform_ok)
{
    unsigned i = blockIdx.x * blockDim.x + threadIdx.x;
    if (i >= (unsigned)total) return;

    // Width probe (R2-proven): pos int32-view word 3 == 0 iff int64 storage.
    const int* pw = (const int*)pos;
    const bool is64 = (pw[3] == 0);   // wave-uniform, L1-hot

    if (is64) {
        sample_body<i64>((const i64*)pos, (const i64*)rand_vals, (const i64*)table,
                         out_neg, out_keep, i, split, L, num_negs, uniform_ok != 0);
    } else {
        sample_body<int>((const int*)pos, (const int*)rand_vals, (const int*)table,
                         out_neg, out_keep, i, split, L, num_negs, uniform_ok != 0);
    }
}

extern "C" void kernel_launch(void* const* d_in, const int* in_sizes, int n_in,
                              void* d_out, int out_size, void* d_ws, size_t ws_size,
                              hipStream_t stream) {
    const void* pos       = d_in[0];
    const void* rand_vals = d_in[1];
    const void* table     = d_in[2];

    const int B     = in_sizes[0] / 3;
    const int total = in_sizes[1];
    const int L     = in_sizes[2];
    const unsigned num_negs = (unsigned)(total / B);
    const int split = (total + 1) / 2;   // ceil(total/2)

    // Tail fast path is valid only if every wave is uniformly head- or
    // tail-corrupt and shares one positive triple.
    const int uniform_ok = (num_negs % 64u == 0u) && (split % 64 == 0);

    int* out_neg  = (int*)d_out;
    int* out_keep = out_neg + (size_t)total * 3;

    const int threads = 256;
    const int blocks  = (total + threads - 1) / threads;
    neg_sample_kernel<<<blocks, threads, 0, stream>>>(
        pos, rand_vals, table, out_neg, out_keep, total, split, L, num_negs,
        uniform_ok);
}

// Round 9
// 96.551 us; speedup vs baseline: 1.3018x; 1.3018x over previous
//
#include <hip/hip_runtime.h>

typedef long long i64;
typedef unsigned long long u64;

// ---------------------------------------------------------------------------
// Established facts (R1-R8):
//  - int64 inputs; int32 output [total*3] neg then [total] keep.
//  - R4/R8: PASS, ~53 us, VALUBusy ~45%, occ ~71%, FETCH 9.5 MB, WRITE 65.5 MB.
//  - R8 (broadcast tail search, 64->1 lines/level for half the grid): NEUTRAL
//    => gather/L2 bandwidth is NOT the limiter; kernel is bound by VALU issue
//    + the 20-deep dependent-load chain of binary search.
//  - Abort rounds (R1,R5,R6,R7) are unreliable evidence (R1's kernel later
//    proven innocent); still, stay in the proven shell: ONE dispatch, width
//    probe, no d_ws, no atomics, no cross-lane intrinsics.
// This round: INTERPOLATION search. Keys are hashes of uniform ids => ~uniform
// over [table[0], table[L-1]]; interpolation converges in ~3-4 probes
// (chain 20 -> ~5) and needs fewer VALU ops. Membership-only (no index).
// Iteration cap + binary fallback => correctness never depends on the
// distribution assumption.
// ---------------------------------------------------------------------------

template <typename T>
__device__ __forceinline__ bool interp_member(const T* __restrict__ table,
                                              int L, u64 key) {
    u64 v0 = (u64)table[0];
    u64 vN = (u64)table[L - 1];
    if (key <= v0) return key == v0;
    if (key >= vN) return key == vN;
    // invariant: table[lo] < key < table[hi]
    int lo = 0, hi = L - 1;
    u64 vlo = v0, vhi = vN;
    for (int it = 0; it < 12 && hi - lo > 8; ++it) {
        // f32 is plenty: rounding error ~ window * 6e-8 < 1 entry.
        float f = (float)(key - vlo) * __builtin_amdgcn_rcpf((float)(vhi - vlo));
        int mid = lo + (int)(f * (float)(hi - lo));
        if (mid <= lo) mid = lo + 1;           // clamp => strict shrink both ways
        if (mid >= hi) mid = hi - 1;
        u64 v = (u64)table[mid];
        if (v == key) return true;
        if (v < key) { lo = mid; vlo = v; }
        else         { hi = mid; vhi = v; }
    }
    while (hi - lo > 8) {                      // fallback; w.h.p. never runs
        int mid = lo + ((hi - lo) >> 1);
        u64 v = (u64)table[mid];
        if (v == key) return true;
        if (v < key) lo = mid; else hi = mid;
    }
    bool eq = false;                           // scan (lo,hi): <=7 independent loads
    for (int j = lo + 1; j < hi; ++j) eq |= ((u64)table[j] == key);
    return eq;
}

template <typename T>
__device__ __forceinline__ void sample_body(
    const T* __restrict__ pos, const T* __restrict__ rand_vals,
    const T* __restrict__ table,
    int* __restrict__ out_neg, int* __restrict__ out_keep,
    unsigned i, int split, int L, unsigned num_negs)
{
    unsigned b = i / num_negs;   // num_negs=64 -> shift
    i64 h = (i64)pos[3 * b + 0];
    i64 r = (i64)pos[3 * b + 1];
    i64 t = (i64)pos[3 * b + 2];
    i64 rv = (i64)rand_vals[i];

    const bool corrupt_head = (i < (unsigned)split);
    i64 orig = corrupt_head ? h : t;
    // pad_idx==0 fast path: rng drawn in [1, NUM_ENTITIES); shift past original
    i64 repl = rv + (((rv >= orig) & (orig > 0)) ? 1 : 0);
    if (corrupt_head) h = repl; else t = repl;

    u64 key = ((u64)h << 42) | ((u64)r << 21) | (u64)t;
    bool in_set = interp_member(table, L, key);

    out_neg[3 * (size_t)i + 0] = (int)h;
    out_neg[3 * (size_t)i + 1] = (int)r;
    out_neg[3 * (size_t)i + 2] = (int)t;
    out_keep[i] = in_set ? 0 : 1;
}

__global__ __launch_bounds__(256) void neg_sample_kernel(
    const void* __restrict__ pos, const void* __restrict__ rand_vals,
    const void* __restrict__ table,
    int* __restrict__ out_neg, int* __restrict__ out_keep,
    int total, int split, int L, unsigned num_negs)
{
    unsigned i = blockIdx.x * blockDim.x + threadIdx.x;
    if (i >= (unsigned)total) return;

    // Width probe (R2-proven): pos int32-view word 3 == 0 iff int64 storage.
    const int* pw = (const int*)pos;
    const bool is64 = (pw[3] == 0);   // wave-uniform, L1-hot

    if (is64) {
        sample_body<i64>((const i64*)pos, (const i64*)rand_vals, (const i64*)table,
                         out_neg, out_keep, i, split, L, num_negs);
    } else {
        sample_body<int>((const int*)pos, (const int*)rand_vals, (const int*)table,
                         out_neg, out_keep, i, split, L, num_negs);
    }
}

extern "C" void kernel_launch(void* const* d_in, const int* in_sizes, int n_in,
                              void* d_out, int out_size, void* d_ws, size_t ws_size,
                              hipStream_t stream) {
    const void* pos       = d_in[0];
    const void* rand_vals = d_in[1];
    const void* table     = d_in[2];

    const int B     = in_sizes[0] / 3;
    const int total = in_sizes[1];
    const int L     = in_sizes[2];
    const unsigned num_negs = (unsigned)(total / B);
    const int split = (total + 1) / 2;   // ceil(total/2)

    int* out_neg  = (int*)d_out;
    int* out_keep = out_neg + (size_t)total * 3;

    const int threads = 256;
    const int blocks  = (total + threads - 1) / threads;
    neg_sample_kernel<<<blocks, threads, 0, stream>>>(
        pos, rand_vals, table, out_neg, out_keep, total, split, L, num_negs);
}